// Round 10
// baseline (359.124 us; speedup 1.0000x reference)
//
#include <hip/hip_runtime.h>
#include <hip/hip_bf16.h>

#define N_ROIS 512
#define P_PTS  128
#define C_CH   256
#define TILE_P 32
#define N_TILES (P_PTS / TILE_P)   // 4

// ---- transposed bf16-level element offsets in workspace ----
#define L0_OFS 0
#define L1_OFS 33554432u
#define L2_OFS 41943040u
#define L3_OFS 44040192u
#define WS_ELEMS_NEEDED 44564480u   // *2 B = 89,128,960 bytes

__device__ inline unsigned pack_bf16x2(float lo, float hi) {
    __hip_bfloat162 h = __float22bfloat162_rn(make_float2(lo, hi));
    unsigned r;
    __builtin_memcpy(&r, &h, 4);
    return r;
}
__device__ inline float bf16_lo(unsigned u) {
    return __uint_as_float(u << 16);
}
__device__ inline float bf16_hi(unsigned u) {
    return __uint_as_float(u & 0xffff0000u);
}

// ---------------- fused NCHW f32 -> NHWC bf16 transpose (all 4 levels) ----------------
__global__ __launch_bounds__(256) void transpose_all_bf16(
    const float* __restrict__ f0, const float* __restrict__ f1,
    const float* __restrict__ f2, const float* __restrict__ f3,
    unsigned short* __restrict__ ws)
{
    const float* in; unsigned short* outp; int HW, pt;
    const int px = blockIdx.x;
    if (px < 32)        { in = f3; outp = ws + L3_OFS; HW = 1024;  pt = px; }
    else if (px < 160)  { in = f2; outp = ws + L2_OFS; HW = 4096;  pt = px - 32; }
    else if (px < 672)  { in = f1; outp = ws + L1_OFS; HW = 16384; pt = px - 160; }
    else                { in = f0; outp = ws + L0_OFS; HW = 65536; pt = px - 672; }

    __shared__ float tile[32][33];
    const int pix0 = pt * 32;
    const int c0   = blockIdx.y * 32;
    const int b    = blockIdx.z;
    in   += (size_t)b * C_CH * HW;
    outp += (size_t)b * C_CH * HW;
    const int tx = threadIdx.x;   // 0..31
    const int ty = threadIdx.y;   // 0..7

    #pragma unroll
    for (int i = 0; i < 32; i += 8)
        tile[ty + i][tx] = in[(size_t)(c0 + ty + i) * HW + pix0 + tx];
    __syncthreads();

    const int tid2 = ty * 32 + tx;
    const int wpix = tid2 >> 3;      // 0..31
    const int wq   = tid2 & 7;       // channel quad within 32-ch group
    uint2 pk;
    pk.x = pack_bf16x2(tile[wq * 4 + 0][wpix], tile[wq * 4 + 1][wpix]);
    pk.y = pack_bf16x2(tile[wq * 4 + 2][wpix], tile[wq * 4 + 3][wpix]);
    *((uint2*)(outp + (size_t)(pix0 + wpix) * C_CH + c0 + wq * 4)) = pk;
}

// ---------------- sampler v8: x-pair dwordx4 gathers + half-wave combine ----------------
__global__ __launch_bounds__(512, 6) void mpe_sample_v8(
    const unsigned short* __restrict__ fT,
    const float* __restrict__ rois, const float* __restrict__ points,
    float* __restrict__ out)
{
    const int n   = blockIdx.x & (N_ROIS - 1);
    const int lvl = 3 - (blockIdx.x >> 9);

    int H; float inv_stride; size_t lofs;
    if      (lvl == 0) { H = 256; inv_stride = 0.25f;    lofs = L0_OFS; }
    else if (lvl == 1) { H = 128; inv_stride = 0.125f;   lofs = L1_OFS; }
    else if (lvl == 2) { H = 64;  inv_stride = 0.0625f;  lofs = L2_OFS; }
    else               { H = 32;  inv_stride = 0.03125f; lofs = L3_OFS; }
    const int W  = H;
    const int HW = H * W;
    const unsigned short* feat = fT + lofs;

    __shared__ int2     s_off2[P_PTS];           // 1 KB: row base pixel idx (y0-row, y1-row)
    __shared__ float4   s_w4[P_PTS];             // 2 KB: weights on clamped 2x2 grid
    __shared__ unsigned s_t2[TILE_P / 2][C_CH];  // 16 KB: [point-pair][channel] bf16x2

    const int tid = threadIdx.x;   // 0..511

    if (tid < P_PTS) {
        const int p = tid;
        const float bx = rois[n * 5 + 0];
        const float x1 = rois[n * 5 + 1];
        const float y1 = rois[n * 5 + 2];
        const float x2 = rois[n * 5 + 3];
        const float y2 = rois[n * 5 + 4];
        const float ptx = points[(n * P_PTS + p) * 2 + 0];
        const float pty = points[(n * P_PTS + p) * 2 + 1];

        const float cx = x1 + ptx * (x2 - x1);
        const float cy = y1 + pty * (y2 - y1);
        const float px = cx * inv_stride - 0.5f;
        const float py = cy * inv_stride - 0.5f;
        const float x0f = floorf(px);
        const float y0f = floorf(py);
        const float wx = px - x0f;
        const float wy = py - y0f;
        const int x0 = (int)x0f;
        const int y0 = (int)y0f;
        const int base = (int)bx * HW;

        // clamped 2-wide x-block [xb, xb+1]; rebin x-weights onto it
        const int xb = min(max(x0, 0), W - 2);
        const bool xv0 = (x0 >= 0) & (x0 < W);
        const bool xv1 = (x0 + 1 >= 0) & (x0 + 1 < W);
        const int xc0 = min(max(x0, 0), W - 1);
        const int xc1 = min(max(x0 + 1, 0), W - 1);
        float xw0 = 0.f, xw1 = 0.f;
        if (xv0) { if (xc0 == xb) xw0 += 1.0f - wx; else xw1 += 1.0f - wx; }
        if (xv1) { if (xc1 == xb) xw0 += wx;        else xw1 += wx; }

        const bool yv0 = (y0 >= 0) & (y0 < H);
        const bool yv1 = (y0 + 1 >= 0) & (y0 + 1 < H);
        const float yw0 = yv0 ? (1.0f - wy) : 0.0f;
        const float yw1 = yv1 ? wy : 0.0f;
        const int yc0 = min(max(y0, 0), H - 1);
        const int yc1 = min(max(y0 + 1, 0), H - 1);

        s_off2[p] = make_int2(base + yc0 * W + xb, base + yc1 * W + xb);
        s_w4[p]   = make_float4(yw0 * xw0, yw0 * xw1, yw1 * xw0, yw1 * xw1);
    }
    __syncthreads();

    const int wave = tid >> 6;      // 0..7
    const int lane = tid & 63;
    const int h    = lane >> 5;     // 0: pixel xb, 1: pixel xb+1
    const int cl   = lane & 31;     // channel-octet index: channels 8*cl..8*cl+7

    // prologue: gather tile 0 (4 points x 2 rows = 8 dwordx4 in flight)
    uint4 v[4][2];
    #pragma unroll
    for (int j = 0; j < 4; ++j) {
        const int2 o = s_off2[wave * 4 + j];
        v[j][0] = *((const uint4*)(feat + (size_t)o.x * C_CH) + lane);
        v[j][1] = *((const uint4*)(feat + (size_t)o.y * C_CH) + lane);
    }

    // store-phase mapping: channel = tid>>1, half = tid&1 (full 128 B lines/wave)
    const int sc = tid >> 1;
    const int sh = tid & 1;
    float* const ob_base = out + ((size_t)n * 1024 + (size_t)lvl * 256 + sc) * P_PTS;

    for (int t = 0; t < N_TILES; ++t) {
        const int pbase = t * TILE_P + wave * 4;

        // ---- compute (consumes v): per point 8 channels of half-column partials ----
        float tt[4][8];
        #pragma unroll
        for (int j = 0; j < 4; ++j) {
            const float4 wj = s_w4[pbase + j];
            const float w0 = h ? wj.y : wj.x;   // weight of this half's pixel, y0-row
            const float w1 = h ? wj.w : wj.z;   // y1-row
            const uint4 a = v[j][0];
            const uint4 b = v[j][1];
            tt[j][0] = bf16_lo(a.x) * w0 + bf16_lo(b.x) * w1;
            tt[j][1] = bf16_hi(a.x) * w0 + bf16_hi(b.x) * w1;
            tt[j][2] = bf16_lo(a.y) * w0 + bf16_lo(b.y) * w1;
            tt[j][3] = bf16_hi(a.y) * w0 + bf16_hi(b.y) * w1;
            tt[j][4] = bf16_lo(a.z) * w0 + bf16_lo(b.z) * w1;
            tt[j][5] = bf16_hi(a.z) * w0 + bf16_hi(b.z) * w1;
            tt[j][6] = bf16_lo(a.w) * w0 + bf16_lo(b.w) * w1;
            tt[j][7] = bf16_hi(a.w) * w0 + bf16_hi(b.w) * w1;
        }
        // combine the two x-halves (lane l <-> l^32), every lane ends with full sums
        #pragma unroll
        for (int j = 0; j < 4; ++j)
            #pragma unroll
            for (int c = 0; c < 8; ++c)
                tt[j][c] += __shfl_xor(tt[j][c], 32);

        // pair-pack (points 2m, 2m+1) and stage: lane writes channels 8*cl+4h..+3
        #pragma unroll
        for (int m = 0; m < 2; ++m) {
            const int hb = h * 4;
            uint4 pk;
            pk.x = pack_bf16x2(tt[2*m][hb+0], tt[2*m+1][hb+0]);
            pk.y = pack_bf16x2(tt[2*m][hb+1], tt[2*m+1][hb+1]);
            pk.z = pack_bf16x2(tt[2*m][hb+2], tt[2*m+1][hb+2]);
            pk.w = pack_bf16x2(tt[2*m][hb+3], tt[2*m+1][hb+3]);
            *((uint4*)&s_t2[wave * 2 + m][cl * 8 + hb]) = pk;
        }

        // ---- issue next tile's gathers; stay in flight across barriers ----
        if (t < N_TILES - 1) {
            const int pnext = pbase + TILE_P;
            #pragma unroll
            for (int j = 0; j < 4; ++j) {
                const int2 o = s_off2[pnext + j];
                v[j][0] = *((const uint4*)(feat + (size_t)o.x * C_CH) + lane);
                v[j][1] = *((const uint4*)(feat + (size_t)o.y * C_CH) + lane);
            }
        }

        // barrier 1: LDS drain only (vmem prefetch survives)
        asm volatile("s_waitcnt lgkmcnt(0)" ::: "memory");
        __builtin_amdgcn_s_barrier();
        __builtin_amdgcn_sched_barrier(0);

        // ---- store phase: 16 consecutive floats at channel sc ----
        float o16[16];
        #pragma unroll
        for (int q = 0; q < 8; ++q) {
            const unsigned u = s_t2[sh * 8 + q][sc];
            o16[2*q]   = bf16_lo(u);
            o16[2*q+1] = bf16_hi(u);
        }
        float* ob = ob_base + t * TILE_P + sh * 16;
        #pragma unroll
        for (int i4 = 0; i4 < 4; ++i4)
            *((float4*)(ob + i4 * 4)) =
                make_float4(o16[i4*4], o16[i4*4+1], o16[i4*4+2], o16[i4*4+3]);

        // barrier 2: store-phase ds_reads done before next compute overwrites s_t2
        asm volatile("s_waitcnt lgkmcnt(0)" ::: "memory");
        __builtin_amdgcn_s_barrier();
        __builtin_amdgcn_sched_barrier(0);
    }
}

// ---------------- fallback (R1 kernel) if workspace too small ----------------
__global__ __launch_bounds__(256) void mpe_sample_nchw(
    const float* __restrict__ feat0, const float* __restrict__ feat1,
    const float* __restrict__ feat2, const float* __restrict__ feat3,
    const float* __restrict__ rois,  const float* __restrict__ points,
    float* __restrict__ out)
{
    const int blk = blockIdx.x;
    const int n   = blk >> 2;
    const int lvl = blk & 3;

    const float* feat;
    int H; float inv_stride;
    if      (lvl == 0) { feat = feat0; H = 256; inv_stride = 0.25f;    }
    else if (lvl == 1) { feat = feat1; H = 128; inv_stride = 0.125f;   }
    else if (lvl == 2) { feat = feat2; H = 64;  inv_stride = 0.0625f;  }
    else               { feat = feat3; H = 32;  inv_stride = 0.03125f; }
    const int W  = H;
    const int HW = H * W;

    __shared__ int   s_off[4][P_PTS];
    __shared__ float s_w[4][P_PTS];
    const int tid = threadIdx.x;

    if (tid < P_PTS) {
        const int p = tid;
        const float bx = rois[n * 5 + 0];
        const float x1 = rois[n * 5 + 1];
        const float y1 = rois[n * 5 + 2];
        const float x2 = rois[n * 5 + 3];
        const float y2 = rois[n * 5 + 4];
        const float ptx = points[(n * P_PTS + p) * 2 + 0];
        const float pty = points[(n * P_PTS + p) * 2 + 1];
        const float cx = x1 + ptx * (x2 - x1);
        const float cy = y1 + pty * (y2 - y1);
        const float px = cx * inv_stride - 0.5f;
        const float py = cy * inv_stride - 0.5f;
        const float x0f = floorf(px);
        const float y0f = floorf(py);
        const float wx = px - x0f;
        const float wy = py - y0f;
        const int x0 = (int)x0f;
        const int y0 = (int)y0f;
        const int base = (int)bx * C_CH * HW;
        #pragma unroll
        for (int k = 0; k < 4; ++k) {
            const int xi = x0 + (k & 1);
            const int yi = y0 + (k >> 1);
            const bool valid = (xi >= 0) & (xi < W) & (yi >= 0) & (yi < H);
            const int xc = min(max(xi, 0), W - 1);
            const int yc = min(max(yi, 0), H - 1);
            const float wk = ((k & 1) ? wx : 1.0f - wx) *
                             ((k >> 1) ? wy : 1.0f - wy);
            s_off[k][p] = base + yc * W + xc;
            s_w[k][p]   = valid ? wk : 0.0f;
        }
    }
    __syncthreads();

    const int p  = tid & (P_PTS - 1);
    const int c0 = tid >> 7;
    const int   off0 = s_off[0][p], off1 = s_off[1][p],
                off2 = s_off[2][p], off3 = s_off[3][p];
    const float w0 = s_w[0][p], w1 = s_w[1][p],
                w2 = s_w[2][p], w3 = s_w[3][p];
    const float* p0 = feat + off0 + c0 * HW;
    const float* p1 = feat + off1 + c0 * HW;
    const float* p2 = feat + off2 + c0 * HW;
    const float* p3 = feat + off3 + c0 * HW;
    float* po = out + ((size_t)n * 1024 + (size_t)lvl * 256 + c0) * P_PTS + p;
    const int step = 2 * HW;
    #pragma unroll 4
    for (int pass = 0; pass < C_CH / 2; ++pass) {
        *po = p0[0] * w0 + p1[0] * w1 + p2[0] * w2 + p3[0] * w3;
        p0 += step; p1 += step; p2 += step; p3 += step;
        po += 2 * P_PTS;
    }
}

extern "C" void kernel_launch(void* const* d_in, const int* in_sizes, int n_in,
                              void* d_out, int out_size, void* d_ws, size_t ws_size,
                              hipStream_t stream) {
    const float* feat0  = (const float*)d_in[0];
    const float* feat1  = (const float*)d_in[1];
    const float* feat2  = (const float*)d_in[2];
    const float* feat3  = (const float*)d_in[3];
    const float* rois   = (const float*)d_in[4];
    const float* points = (const float*)d_in[5];
    float* out = (float*)d_out;

    if (ws_size >= (size_t)WS_ELEMS_NEEDED * 2u) {
        unsigned short* fT = (unsigned short*)d_ws;
        transpose_all_bf16<<<dim3(2720, 8, 2), dim3(32, 8), 0, stream>>>(
            feat0, feat1, feat2, feat3, fT);
        mpe_sample_v8<<<dim3(N_ROIS * 4), dim3(512), 0, stream>>>(
            fT, rois, points, out);
    } else {
        mpe_sample_nchw<<<dim3(N_ROIS * 4), dim3(256), 0, stream>>>(
            feat0, feat1, feat2, feat3, rois, points, out);
    }
}

// Round 11
// 187.481 us; speedup vs baseline: 1.9155x; 1.9155x over previous
//
#include <hip/hip_runtime.h>
#include <hip/hip_bf16.h>

#define N_ROIS 512
#define P_PTS  128
#define C_CH   256
#define TILE_P 32
#define N_TILES (P_PTS / TILE_P)   // 4

// ---- transposed bf16-level element offsets in workspace ----
#define L0_OFS 0
#define L1_OFS 33554432u
#define L2_OFS 41943040u
#define L3_OFS 44040192u
#define WS_ELEMS_NEEDED 44564480u   // *2 B = 89,128,960 bytes

__device__ inline unsigned pack_bf16x2(float lo, float hi) {
    __hip_bfloat162 h = __float22bfloat162_rn(make_float2(lo, hi));
    unsigned r;
    __builtin_memcpy(&r, &h, 4);
    return r;
}
__device__ inline float bf16_lo(unsigned u) {
    return __uint_as_float(u << 16);
}
__device__ inline float bf16_hi(unsigned u) {
    return __uint_as_float(u & 0xffff0000u);
}

// ---------------- fused NCHW f32 -> NHWC bf16 transpose (all 4 levels) ----------------
__global__ __launch_bounds__(256) void transpose_all_bf16(
    const float* __restrict__ f0, const float* __restrict__ f1,
    const float* __restrict__ f2, const float* __restrict__ f3,
    unsigned short* __restrict__ ws)
{
    const float* in; unsigned short* outp; int HW, pt;
    const int px = blockIdx.x;
    if (px < 32)        { in = f3; outp = ws + L3_OFS; HW = 1024;  pt = px; }
    else if (px < 160)  { in = f2; outp = ws + L2_OFS; HW = 4096;  pt = px - 32; }
    else if (px < 672)  { in = f1; outp = ws + L1_OFS; HW = 16384; pt = px - 160; }
    else                { in = f0; outp = ws + L0_OFS; HW = 65536; pt = px - 672; }

    __shared__ float tile[32][33];
    const int pix0 = pt * 32;
    const int c0   = blockIdx.y * 32;
    const int b    = blockIdx.z;
    in   += (size_t)b * C_CH * HW;
    outp += (size_t)b * C_CH * HW;
    const int tx = threadIdx.x;   // 0..31
    const int ty = threadIdx.y;   // 0..7

    #pragma unroll
    for (int i = 0; i < 32; i += 8)
        tile[ty + i][tx] = in[(size_t)(c0 + ty + i) * HW + pix0 + tx];
    __syncthreads();

    const int tid2 = ty * 32 + tx;
    const int wpix = tid2 >> 3;      // 0..31
    const int wq   = tid2 & 7;       // channel quad within 32-ch group
    uint2 pk;
    pk.x = pack_bf16x2(tile[wq * 4 + 0][wpix], tile[wq * 4 + 1][wpix]);
    pk.y = pack_bf16x2(tile[wq * 4 + 2][wpix], tile[wq * 4 + 3][wpix]);
    *((uint2*)(outp + (size_t)(pix0 + wpix) * C_CH + c0 + wq * 4)) = pk;
}

// ---------------- sampler v9: v7 + 128-VGPR budget + single-barrier dbuf ----------------
__global__ __launch_bounds__(512, 4) void mpe_sample_v9(
    const unsigned short* __restrict__ fT,
    const float* __restrict__ rois, const float* __restrict__ points,
    float* __restrict__ out)
{
    const int n   = blockIdx.x & (N_ROIS - 1);
    const int lvl = 3 - (blockIdx.x >> 9);

    int H; float inv_stride; size_t lofs;
    if      (lvl == 0) { H = 256; inv_stride = 0.25f;    lofs = L0_OFS; }
    else if (lvl == 1) { H = 128; inv_stride = 0.125f;   lofs = L1_OFS; }
    else if (lvl == 2) { H = 64;  inv_stride = 0.0625f;  lofs = L2_OFS; }
    else               { H = 32;  inv_stride = 0.03125f; lofs = L3_OFS; }
    const int W  = H;
    const int HW = H * W;
    const unsigned short* feat = fT + lofs;

    __shared__ int4     s_off4[P_PTS];              // 2 KB
    __shared__ float4   s_w4[P_PTS];                // 2 KB
    __shared__ unsigned s_t2[2][TILE_P / 2][C_CH];  // 32 KB double-buffered staging

    const int tid = threadIdx.x;   // 0..511

    if (tid < P_PTS) {
        const int p = tid;
        const float bx = rois[n * 5 + 0];
        const float x1 = rois[n * 5 + 1];
        const float y1 = rois[n * 5 + 2];
        const float x2 = rois[n * 5 + 3];
        const float y2 = rois[n * 5 + 4];
        const float ptx = points[(n * P_PTS + p) * 2 + 0];
        const float pty = points[(n * P_PTS + p) * 2 + 1];

        const float cx = x1 + ptx * (x2 - x1);
        const float cy = y1 + pty * (y2 - y1);
        const float px = cx * inv_stride - 0.5f;
        const float py = cy * inv_stride - 0.5f;
        const float x0f = floorf(px);
        const float y0f = floorf(py);
        const float wx = px - x0f;
        const float wy = py - y0f;
        const int x0 = (int)x0f;
        const int y0 = (int)y0f;
        const int base = (int)bx * HW;

        int   o[4]; float w[4];
        #pragma unroll
        for (int k = 0; k < 4; ++k) {
            const int xi = x0 + (k & 1);
            const int yi = y0 + (k >> 1);
            const bool valid = (xi >= 0) & (xi < W) & (yi >= 0) & (yi < H);
            const int xc = min(max(xi, 0), W - 1);
            const int yc = min(max(yi, 0), H - 1);
            const float wk = ((k & 1) ? wx : 1.0f - wx) *
                             ((k >> 1) ? wy : 1.0f - wy);
            o[k] = base + yc * W + xc;
            w[k] = valid ? wk : 0.0f;
        }
        s_off4[p] = make_int4(o[0], o[1], o[2], o[3]);
        s_w4[p]   = make_float4(w[0], w[1], w[2], w[3]);
    }
    __syncthreads();

    const int wave = tid >> 6;     // 0..7
    const int lane = tid & 63;     // lane = channel-quad (4 bf16 = 8 B)

    // prologue: gather tile 0 (4 points x 4 corners = 16 dwordx2 in flight)
    uint2 v[4][4];
    #pragma unroll
    for (int j = 0; j < 4; ++j) {
        const int4 o = s_off4[wave * 4 + j];
        v[j][0] = *((const uint2*)(feat + (size_t)o.x * C_CH) + lane);
        v[j][1] = *((const uint2*)(feat + (size_t)o.y * C_CH) + lane);
        v[j][2] = *((const uint2*)(feat + (size_t)o.z * C_CH) + lane);
        v[j][3] = *((const uint2*)(feat + (size_t)o.w * C_CH) + lane);
    }

    // store-phase mapping: channel = tid>>1, half = tid&1 (full 128 B lines/wave)
    const int sc = tid >> 1;
    const int sh = tid & 1;
    float* const ob_base = out + ((size_t)n * 1024 + (size_t)lvl * 256 + sc) * P_PTS;

    for (int t = 0; t < N_TILES; ++t) {
        const int b = t & 1;
        const int pbase = t * TILE_P + wave * 4;

        // ---- compute (consumes v) + pair-pack + LDS write into buffer b ----
        float a[4][4];
        #pragma unroll
        for (int j = 0; j < 4; ++j) {
            const float4 wj = s_w4[pbase + j];
            float ax = 0.f, ay = 0.f, az = 0.f, aw = 0.f;
            #pragma unroll
            for (int k = 0; k < 4; ++k) {
                const float wk = (k == 0) ? wj.x : (k == 1) ? wj.y : (k == 2) ? wj.z : wj.w;
                ax = fmaf(bf16_lo(v[j][k].x), wk, ax);
                ay = fmaf(bf16_hi(v[j][k].x), wk, ay);
                az = fmaf(bf16_lo(v[j][k].y), wk, az);
                aw = fmaf(bf16_hi(v[j][k].y), wk, aw);
            }
            a[j][0] = ax; a[j][1] = ay; a[j][2] = az; a[j][3] = aw;
        }
        #pragma unroll
        for (int m = 0; m < 2; ++m) {   // point pairs (2m, 2m+1)
            uint4 pk;
            pk.x = pack_bf16x2(a[2*m][0], a[2*m+1][0]);
            pk.y = pack_bf16x2(a[2*m][1], a[2*m+1][1]);
            pk.z = pack_bf16x2(a[2*m][2], a[2*m+1][2]);
            pk.w = pack_bf16x2(a[2*m][3], a[2*m+1][3]);
            *((uint4*)&s_t2[b][wave * 2 + m][lane * 4]) = pk;
        }

        // ---- issue next tile's gathers; they stay in flight across the barrier ----
        if (t < N_TILES - 1) {
            const int pnext = pbase + TILE_P;
            #pragma unroll
            for (int j = 0; j < 4; ++j) {
                const int4 o = s_off4[pnext + j];
                v[j][0] = *((const uint2*)(feat + (size_t)o.x * C_CH) + lane);
                v[j][1] = *((const uint2*)(feat + (size_t)o.y * C_CH) + lane);
                v[j][2] = *((const uint2*)(feat + (size_t)o.z * C_CH) + lane);
                v[j][3] = *((const uint2*)(feat + (size_t)o.w * C_CH) + lane);
            }
        }

        // single barrier per tile: LDS drain only (vmem prefetch survives).
        // Next tile writes the OTHER staging buffer, so no write-after-read
        // hazard on s_t2[b] and no second barrier is needed.
        asm volatile("s_waitcnt lgkmcnt(0)" ::: "memory");
        __builtin_amdgcn_s_barrier();
        __builtin_amdgcn_sched_barrier(0);

        // ---- store phase: 16 consecutive floats at channel sc ----
        float o16[16];
        #pragma unroll
        for (int q = 0; q < 8; ++q) {
            const unsigned u = s_t2[b][sh * 8 + q][sc];
            o16[2*q]   = bf16_lo(u);
            o16[2*q+1] = bf16_hi(u);
        }
        float* ob = ob_base + t * TILE_P + sh * 16;
        #pragma unroll
        for (int i4 = 0; i4 < 4; ++i4)
            *((float4*)(ob + i4 * 4)) =
                make_float4(o16[i4*4], o16[i4*4+1], o16[i4*4+2], o16[i4*4+3]);
    }
}

// ---------------- fallback (R1 kernel) if workspace too small ----------------
__global__ __launch_bounds__(256) void mpe_sample_nchw(
    const float* __restrict__ feat0, const float* __restrict__ feat1,
    const float* __restrict__ feat2, const float* __restrict__ feat3,
    const float* __restrict__ rois,  const float* __restrict__ points,
    float* __restrict__ out)
{
    const int blk = blockIdx.x;
    const int n   = blk >> 2;
    const int lvl = blk & 3;

    const float* feat;
    int H; float inv_stride;
    if      (lvl == 0) { feat = feat0; H = 256; inv_stride = 0.25f;    }
    else if (lvl == 1) { feat = feat1; H = 128; inv_stride = 0.125f;   }
    else if (lvl == 2) { feat = feat2; H = 64;  inv_stride = 0.0625f;  }
    else               { feat = feat3; H = 32;  inv_stride = 0.03125f; }
    const int W  = H;
    const int HW = H * W;

    __shared__ int   s_off[4][P_PTS];
    __shared__ float s_w[4][P_PTS];
    const int tid = threadIdx.x;

    if (tid < P_PTS) {
        const int p = tid;
        const float bx = rois[n * 5 + 0];
        const float x1 = rois[n * 5 + 1];
        const float y1 = rois[n * 5 + 2];
        const float x2 = rois[n * 5 + 3];
        const float y2 = rois[n * 5 + 4];
        const float ptx = points[(n * P_PTS + p) * 2 + 0];
        const float pty = points[(n * P_PTS + p) * 2 + 1];
        const float cx = x1 + ptx * (x2 - x1);
        const float cy = y1 + pty * (y2 - y1);
        const float px = cx * inv_stride - 0.5f;
        const float py = cy * inv_stride - 0.5f;
        const float x0f = floorf(px);
        const float y0f = floorf(py);
        const float wx = px - x0f;
        const float wy = py - y0f;
        const int x0 = (int)x0f;
        const int y0 = (int)y0f;
        const int base = (int)bx * C_CH * HW;
        #pragma unroll
        for (int k = 0; k < 4; ++k) {
            const int xi = x0 + (k & 1);
            const int yi = y0 + (k >> 1);
            const bool valid = (xi >= 0) & (xi < W) & (yi >= 0) & (yi < H);
            const int xc = min(max(xi, 0), W - 1);
            const int yc = min(max(yi, 0), H - 1);
            const float wk = ((k & 1) ? wx : 1.0f - wx) *
                             ((k >> 1) ? wy : 1.0f - wy);
            s_off[k][p] = base + yc * W + xc;
            s_w[k][p]   = valid ? wk : 0.0f;
        }
    }
    __syncthreads();

    const int p  = tid & (P_PTS - 1);
    const int c0 = tid >> 7;
    const int   off0 = s_off[0][p], off1 = s_off[1][p],
                off2 = s_off[2][p], off3 = s_off[3][p];
    const float w0 = s_w[0][p], w1 = s_w[1][p],
                w2 = s_w[2][p], w3 = s_w[3][p];
    const float* p0 = feat + off0 + c0 * HW;
    const float* p1 = feat + off1 + c0 * HW;
    const float* p2 = feat + off2 + c0 * HW;
    const float* p3 = feat + off3 + c0 * HW;
    float* po = out + ((size_t)n * 1024 + (size_t)lvl * 256 + c0) * P_PTS + p;
    const int step = 2 * HW;
    #pragma unroll 4
    for (int pass = 0; pass < C_CH / 2; ++pass) {
        *po = p0[0] * w0 + p1[0] * w1 + p2[0] * w2 + p3[0] * w3;
        p0 += step; p1 += step; p2 += step; p3 += step;
        po += 2 * P_PTS;
    }
}

extern "C" void kernel_launch(void* const* d_in, const int* in_sizes, int n_in,
                              void* d_out, int out_size, void* d_ws, size_t ws_size,
                              hipStream_t stream) {
    const float* feat0  = (const float*)d_in[0];
    const float* feat1  = (const float*)d_in[1];
    const float* feat2  = (const float*)d_in[2];
    const float* feat3  = (const float*)d_in[3];
    const float* rois   = (const float*)d_in[4];
    const float* points = (const float*)d_in[5];
    float* out = (float*)d_out;

    if (ws_size >= (size_t)WS_ELEMS_NEEDED * 2u) {
        unsigned short* fT = (unsigned short*)d_ws;
        transpose_all_bf16<<<dim3(2720, 8, 2), dim3(32, 8), 0, stream>>>(
            feat0, feat1, feat2, feat3, fT);
        mpe_sample_v9<<<dim3(N_ROIS * 4), dim3(512), 0, stream>>>(
            fT, rois, points, out);
    } else {
        mpe_sample_nchw<<<dim3(N_ROIS * 4), dim3(256), 0, stream>>>(
            feat0, feat1, feat2, feat3, rois, points, out);
    }
}